// Round 6
// baseline (118.744 us; speedup 1.0000x reference)
//
#include <hip/hip_runtime.h>

// BiGNN fused MFMA kernel, R6 (f16 everywhere).
// vs R5: weights pre-packed to MFMA frag layout in d_ws (no LDS weight
// staging, no barriers); LDS = p-buffer only (17.4 KB) + launch_bounds(256,4)
// -> 4 blocks/CU; f16 MFMA + packed pk_max reduce with BN sign folded into
// weights at prep time; grid 782, one tile per block, idx loads at entry.

typedef __attribute__((ext_vector_type(8))) _Float16 half8;
typedef __attribute__((ext_vector_type(2))) _Float16 h2;
typedef __attribute__((ext_vector_type(4))) float f32x4;

constexpr int N_ROWS = 50000;
constexpr int M1 = 200000, M2 = 100000;
constexpr int C1 = 32, C2 = 64, CL = 64, CG = 64;
constexpr float EPS = 1e-3f;
constexpr int RPB = 64, RPW = 16;
constexpr int N_TILES = (N_ROWS + RPB - 1) / RPB;     // 782

// ---- LDS: p-transpose buffer only ----
constexpr int P_STRIDE_B = 272;                       // bytes/row (256 + 16 pad)
constexpr int SMEM_BYTES = 64 * P_STRIDE_B;           // 17408

// ---- workspace layout (bytes) ----
constexpr size_t S1_ELEMS = (size_t)M1 * C1;
constexpr size_t S2_ELEMS = (size_t)M2 * C2;
constexpr size_t FR_OFF  = (S1_ELEMS + S2_ELEMS) * 2; // 25,600,000 (16B aligned)
constexpr int    N_FRAGS = 36;                        // 4 W1 + 8 W2 + 24 Wout
constexpr size_t AS2_OFF = FR_OFF + (size_t)N_FRAGS * 64 * 16;  // +36864
constexpr size_t T2_OFF  = AS2_OFF + 256;
constexpr size_t STO_OFF = T2_OFF + 256;
constexpr size_t WS_NEED = STO_OFF + 512;

__device__ __forceinline__ h2 pkrtz(float a, float b) {
    return (h2)__builtin_amdgcn_cvt_pkrtz(a, b);
}
__device__ __forceinline__ h2 pkmax(h2 a, h2 b) {
    h2 d;
    asm("v_pk_max_f16 %0, %1, %2" : "=v"(d) : "v"(a), "v"(b));
    return d;
}
__device__ __forceinline__ h2 shx(h2 a, int m) {
    return __builtin_bit_cast(h2, __shfl_xor(__builtin_bit_cast(int, a), m));
}
__device__ __forceinline__ half8 pack8f(float4 x, float4 y) {
    int4 iv = { __builtin_bit_cast(int, pkrtz(x.x, x.y)),
                __builtin_bit_cast(int, pkrtz(x.z, x.w)),
                __builtin_bit_cast(int, pkrtz(y.x, y.y)),
                __builtin_bit_cast(int, pkrtz(y.z, y.w)) };
    return __builtin_bit_cast(half8, iv);
}
#define MFMA16(a, b, c) __builtin_amdgcn_mfma_f32_16x16x32_f16((a), (b), (c), 0, 0, 0)

// ---- shared frag builders (used by prep_w and the f32 fallback path) ----
// B-frag lane l: N = l&15 (within nt tile), K = (l>>4)*8 + j.
__device__ __forceinline__ half8 wg_frag(const float* __restrict__ W,
                                         const float* __restrict__ bn,
                                         int ck, int nt, int lane) {
    int lc = lane & 15, hi = lane >> 4, d = nt * 16 + lc;
    float s = bn[d] * rsqrtf(bn[192 + d] + EPS);
    float sg = s >= 0.f ? 1.f : -1.f;                 // sign folded into weight
    half8 r;
#pragma unroll
    for (int j = 0; j < 8; ++j)
        r[j] = (_Float16)(W[(ck * 32 + hi * 8 + j) * CG + d] * sg);
    return r;
}
// Wout frag; for p-rows (ck>=2) apply pair-interleave perm pi(q) matching the
// p_lds layout: position q -> channel (q&1) ? 16+(q>>1) : (q>>1).
__device__ __forceinline__ half8 wout_frag(const float* __restrict__ Wout,
                                           int ck, int nt, int lane) {
    int lc = lane & 15, hi = lane >> 4, d = nt * 16 + lc;
    half8 r;
#pragma unroll
    for (int j = 0; j < 8; ++j) {
        int pos = hi * 8 + j, row;
        if (ck < 2) row = ck * 32 + pos;
        else {
            int a = (pos & 1) ? 16 + (pos >> 1) : (pos >> 1);
            row = 64 + (ck - 2) * 32 + a;
        }
        r[j] = (_Float16)Wout[row * CG + d];
    }
    return r;
}

// ---- streaming f32 -> f16 table conversion ----
__global__ __launch_bounds__(256)
void cvt_f16(const float* __restrict__ s1, _Float16* __restrict__ d1, int n1_8,
             const float* __restrict__ s2, _Float16* __restrict__ d2, int n2_8) {
    for (int i = blockIdx.x * blockDim.x + threadIdx.x; i < n1_8 + n2_8;
         i += gridDim.x * blockDim.x) {
        const float* src = i < n1_8 ? s1 + (size_t)i * 8 : s2 + (size_t)(i - n1_8) * 8;
        _Float16* dst = i < n1_8 ? d1 + (size_t)i * 8 : d2 + (size_t)(i - n1_8) * 8;
        const float4* p = (const float4*)src;
        *(half8*)dst = pack8f(p[0], p[1]);
    }
}

// ---- weight frag + BN prep ----
__global__ __launch_bounds__(256)
void prep_w(const float* __restrict__ Wg1, const float* __restrict__ Wg2,
            const float* __restrict__ Wout,
            const float* __restrict__ bn_g1, const float* __restrict__ bn_g2,
            const float* __restrict__ bn_out,
            half8* __restrict__ frags, h2* __restrict__ as2, h2* __restrict__ t2,
            float2* __restrict__ sto) {
    int g = blockIdx.x * 256 + threadIdx.x;
    if (g < N_FRAGS * 64) {
        int fid = g >> 6, lane = g & 63;
        half8 r;
        if (fid < 4)       r = wg_frag(Wg1, bn_g1, 0, fid, lane);
        else if (fid < 12) r = wg_frag(Wg2, bn_g2, (fid - 4) >> 2, (fid - 4) & 3, lane);
        else               r = wout_frag(Wout, (fid - 12) >> 2, (fid - 12) & 3, lane);
        frags[g] = r;
    } else if (g < N_FRAGS * 64 + 64) {               // packed |s|,t for groupers
        int i = g - N_FRAGS * 64, gg = i >> 5, pp = (i >> 4) & 1, lc = i & 15;
        const float* bn = gg ? bn_g2 : bn_g1;
        int c0 = pp * 32 + lc, c1 = c0 + 16;
        float s0 = bn[c0] * rsqrtf(bn[192 + c0] + EPS);
        float s1 = bn[c1] * rsqrtf(bn[192 + c1] + EPS);
        as2[i] = pkrtz(fabsf(s0), fabsf(s1));
        t2[i]  = pkrtz(fmaf(-bn[128 + c0], s0, bn[64 + c0]),
                       fmaf(-bn[128 + c1], s1, bn[64 + c1]));
    } else if (g < N_FRAGS * 64 + 128) {              // out-layer (s,t) f32
        int ch = g - (N_FRAGS * 64 + 64);
        float s = bn_out[ch] * rsqrtf(bn_out[192 + ch] + EPS);
        sto[ch] = make_float2(s, fmaf(-bn_out[128 + ch], s, bn_out[64 + ch]));
    }
}

// load a 4-row gather chunk into register buffers
#define LOAD_CHUNK(RB, B1, B2a, B2b)                                           \
    _Pragma("unroll")                                                          \
    for (int u = 0; u < 4; ++u) {                                              \
        if constexpr (BF) {                                                    \
            B1[u]  = *(const half8*)(s1h + (size_t)nb1[(RB)+u] * C1 + hi*8);   \
            B2a[u] = *(const half8*)(s2h + (size_t)nb2[(RB)+u] * C2 + hi*8);   \
            B2b[u] = *(const half8*)(s2h + (size_t)nb2[(RB)+u] * C2 + 32 + hi*8); \
        } else {                                                               \
            const float4* g1p = (const float4*)(feat_s1 + (size_t)nb1[(RB)+u] * C1 + hi*8); \
            B1[u] = pack8f(g1p[0], g1p[1]);                                    \
            const float4* g2p = (const float4*)(feat_s2 + (size_t)nb2[(RB)+u] * C2 + hi*8); \
            B2a[u] = pack8f(g2p[0], g2p[1]);                                   \
            const float4* g2q = (const float4*)(feat_s2 + (size_t)nb2[(RB)+u] * C2 + 32 + hi*8); \
            B2b[u] = pack8f(g2q[0], g2q[1]);                                   \
        }                                                                      \
    }

// consume a 4-row chunk: 12 MFMA + packed maxpool/BN/ReLU + one LDS write/row
#define COMP_CHUNK(RB, B1, B2a, B2b)                                           \
    _Pragma("unroll")                                                          \
    for (int u = 0; u < 4; ++u) {                                              \
        const int r_ = wave * RPW + (RB) + u;                                  \
        f32x4 z_ = {0.f, 0.f, 0.f, 0.f};                                       \
        f32x4 acc1[4], acc2[4];                                                \
        _Pragma("unroll")                                                      \
        for (int nt = 0; nt < 4; ++nt) acc1[nt] = MFMA16(B1[u], bW1[nt], z_);  \
        _Pragma("unroll")                                                      \
        for (int nt = 0; nt < 4; ++nt) acc2[nt] = MFMA16(B2a[u], bW2[0][nt], z_); \
        _Pragma("unroll")                                                      \
        for (int nt = 0; nt < 4; ++nt) acc2[nt] = MFMA16(B2b[u], bW2[1][nt], acc2[nt]); \
        h2 pv[2][2];                                                           \
        _Pragma("unroll")                                                      \
        for (int pp = 0; pp < 2; ++pp) {                                       \
            h2 x0 = pkrtz(acc1[2*pp][0], acc1[2*pp+1][0]);                     \
            h2 x1 = pkrtz(acc1[2*pp][1], acc1[2*pp+1][1]);                     \
            h2 x2 = pkrtz(acc1[2*pp][2], acc1[2*pp+1][2]);                     \
            h2 x3 = pkrtz(acc1[2*pp][3], acc1[2*pp+1][3]);                     \
            h2 m_ = pkmax(pkmax(x0, x1), pkmax(x2, x3));                       \
            m_ = pkmax(m_, shx(m_, 16));                                       \
            m_ = pkmax(m_, shx(m_, 32));                                       \
            pv[0][pp] = pkmax(m_ * as2g[0][pp] + t2g[0][pp], hz);              \
            h2 y0 = pkrtz(acc2[2*pp][0], acc2[2*pp+1][0]);                     \
            h2 y1 = pkrtz(acc2[2*pp][1], acc2[2*pp+1][1]);                     \
            h2 y2 = pkrtz(acc2[2*pp][2], acc2[2*pp+1][2]);                     \
            h2 y3 = pkrtz(acc2[2*pp][3], acc2[2*pp+1][3]);                     \
            h2 n_ = pkmax(pkmax(y0, y1), pkmax(y2, y3));                       \
            n_ = pkmax(n_, shx(n_, 16));                                       \
            n_ = pkmax(n_, shx(n_, 32));                                       \
            pv[1][pp] = pkmax(n_ * as2g[1][pp] + t2g[1][pp], hz);              \
        }                                                                      \
        h2 w_ = (hi & 2) ? ((hi & 1) ? pv[1][1] : pv[1][0])                    \
                         : ((hi & 1) ? pv[0][1] : pv[0][0]);                   \
        *(h2*)(p_lds + r_ * P_STRIDE_B + hi * 64 + lc * 4) = w_;               \
    }

template<bool BF>
__global__ __launch_bounds__(256, 4)
void bignn_mfma(const float* __restrict__ feat_s1, const float* __restrict__ feat_s2,
                const float* __restrict__ feat_last,
                const float* __restrict__ Wg1, const float* __restrict__ bn_g1,
                const float* __restrict__ Wg2, const float* __restrict__ bn_g2,
                const float* __restrict__ Wout, const float* __restrict__ bn_out,
                const int* __restrict__ idx_s1, const int* __restrict__ idx_s2,
                const _Float16* __restrict__ s1h, const _Float16* __restrict__ s2h,
                const half8* __restrict__ frags, const h2* __restrict__ as2,
                const h2* __restrict__ t2, const float2* __restrict__ sto,
                float* __restrict__ out)
{
    __shared__ __align__(16) char p_lds[SMEM_BYTES];  // [64 rows][272 B]

    const int t    = threadIdx.x;
    const int lane = t & 63, lc = lane & 15, hi = lane >> 4;
    const int wave = t >> 6;
    const int rbase = blockIdx.x * RPB + wave * RPW;
    const h2 hz = {(_Float16)0.f, (_Float16)0.f};

    // neighbor indices -> registers (first loads issued)
    int nb1[RPW], nb2[RPW];
#pragma unroll
    for (int r = 0; r < RPW; ++r) {
        int grow = min(rbase + r, N_ROWS - 1);
        nb1[r] = idx_s1[(size_t)grow * 16 + lc];
        nb2[r] = idx_s2[(size_t)grow * 16 + lc];
    }

    // register-resident B-frags + packed BN consts
    short8_check: ;
    half8 bW1[4], bW2[2][4];
    h2 as2g[2][2], t2g[2][2];
    if constexpr (BF) {
#pragma unroll
        for (int nt = 0; nt < 4; ++nt) bW1[nt] = frags[nt * 64 + lane];
#pragma unroll
        for (int ck = 0; ck < 2; ++ck)
#pragma unroll
            for (int nt = 0; nt < 4; ++nt)
                bW2[ck][nt] = frags[(4 + ck * 4 + nt) * 64 + lane];
#pragma unroll
        for (int g = 0; g < 2; ++g)
#pragma unroll
            for (int pp = 0; pp < 2; ++pp) {
                as2g[g][pp] = as2[g * 32 + pp * 16 + lc];
                t2g[g][pp]  = t2[g * 32 + pp * 16 + lc];
            }
    } else {
#pragma unroll
        for (int nt = 0; nt < 4; ++nt) bW1[nt] = wg_frag(Wg1, bn_g1, 0, nt, lane);
#pragma unroll
        for (int ck = 0; ck < 2; ++ck)
#pragma unroll
            for (int nt = 0; nt < 4; ++nt)
                bW2[ck][nt] = wg_frag(Wg2, bn_g2, ck, nt, lane);
#pragma unroll
        for (int g = 0; g < 2; ++g)
#pragma unroll
            for (int pp = 0; pp < 2; ++pp) {
                const float* bn = g ? bn_g2 : bn_g1;
                int c0 = pp * 32 + lc, c1 = c0 + 16;
                float s0 = bn[c0] * rsqrtf(bn[192 + c0] + EPS);
                float s1 = bn[c1] * rsqrtf(bn[192 + c1] + EPS);
                as2g[g][pp] = pkrtz(fabsf(s0), fabsf(s1));
                t2g[g][pp]  = pkrtz(fmaf(-bn[128 + c0], s0, bn[64 + c0]),
                                    fmaf(-bn[128 + c1], s1, bn[64 + c1]));
            }
    }

    // ---------------- grouper: double-buffered 4-row chunks ----------------
    half8 A1a[4], A2aa[4], A2ba[4];
    half8 A1b[4], A2ab[4], A2bb[4];
    LOAD_CHUNK(0, A1a, A2aa, A2ba);
    LOAD_CHUNK(4, A1b, A2ab, A2bb);
    COMP_CHUNK(0, A1a, A2aa, A2ba);
    LOAD_CHUNK(8, A1a, A2aa, A2ba);
    COMP_CHUNK(4, A1b, A2ab, A2bb);
    LOAD_CHUNK(12, A1b, A2ab, A2bb);
    // feat_last loads issued under the last two COMPs
    const int mrow = min(rbase + lc, N_ROWS - 1);
    const float4* flp = (const float4*)(feat_last + (size_t)mrow * CL + hi * 8);
    float4 f0 = flp[0], f1 = flp[1];
    const float4* flq = (const float4*)(feat_last + (size_t)mrow * CL + 32 + hi * 8);
    float4 f2 = flq[0], f3 = flq[1];
    COMP_CHUNK(8, A1a, A2aa, A2ba);
    COMP_CHUNK(12, A1b, A2ab, A2bb);

    // ---------------- final layer: 16-row M-tile per wave ----------------
    {
        half8 aA = pack8f(f0, f1), aB = pack8f(f2, f3);
        f32x4 facc[4] = {{0.f,0.f,0.f,0.f},{0.f,0.f,0.f,0.f},{0.f,0.f,0.f,0.f},{0.f,0.f,0.f,0.f}};
#pragma unroll
        for (int ck = 0; ck < 6; ++ck) {
            half8 af;
            if (ck == 0) af = aA;
            else if (ck == 1) af = aB;
            else af = *(const half8*)(p_lds + (wave * RPW + lc) * P_STRIDE_B + (ck - 2) * 64 + hi * 16);
#pragma unroll
            for (int nt = 0; nt < 4; ++nt) {
                half8 bf;
                if constexpr (BF) bf = frags[(12 + ck * 4 + nt) * 64 + lane];
                else              bf = wout_frag(Wout, ck, nt, lane);
                facc[nt] = MFMA16(af, bf, facc[nt]);
            }
        }
#pragma unroll
        for (int nt = 0; nt < 4; ++nt) {
            float2 so;
            if constexpr (BF) so = sto[nt * 16 + lc];
            else {
                int ch = nt * 16 + lc;
                float s = bn_out[ch] * rsqrtf(bn_out[192 + ch] + EPS);
                so = make_float2(s, fmaf(-bn_out[128 + ch], s, bn_out[64 + ch]));
            }
#pragma unroll
            for (int rg = 0; rg < 4; ++rg) {
                int grow = rbase + hi * 4 + rg;
                if (grow < N_ROWS) {
                    float v = fmaxf(0.f, fmaf(so.x, facc[nt][rg], so.y));
                    out[(size_t)grow * CG + nt * 16 + lc] = v;
                }
            }
        }
    }
}

extern "C" void kernel_launch(void* const* d_in, const int* in_sizes, int n_in,
                              void* d_out, int out_size, void* d_ws, size_t ws_size,
                              hipStream_t stream) {
    const float* feat_s1   = (const float*)d_in[0];
    const float* feat_s2   = (const float*)d_in[1];
    const float* feat_last = (const float*)d_in[2];
    const float* Wg1       = (const float*)d_in[3];
    const float* bn_g1     = (const float*)d_in[4];
    const float* Wg2       = (const float*)d_in[5];
    const float* bn_g2     = (const float*)d_in[6];
    const float* Wout      = (const float*)d_in[7];
    const float* bn_out    = (const float*)d_in[8];
    const int*   idx_s1    = (const int*)d_in[9];
    const int*   idx_s2    = (const int*)d_in[10];
    float* out = (float*)d_out;

    if (ws_size >= WS_NEED) {
        _Float16* s1h = (_Float16*)d_ws;
        _Float16* s2h = s1h + S1_ELEMS;
        half8*  frags = (half8*)((char*)d_ws + FR_OFF);
        h2*     as2   = (h2*)((char*)d_ws + AS2_OFF);
        h2*     t2p   = (h2*)((char*)d_ws + T2_OFF);
        float2* sto   = (float2*)((char*)d_ws + STO_OFF);
        cvt_f16<<<2048, 256, 0, stream>>>(feat_s1, s1h, (int)(S1_ELEMS / 8),
                                          feat_s2, s2h, (int)(S2_ELEMS / 8));
        prep_w<<<10, 256, 0, stream>>>(Wg1, Wg2, Wout, bn_g1, bn_g2, bn_out,
                                       frags, as2, t2p, sto);
        bignn_mfma<true><<<N_TILES, dim3(256), 0, stream>>>(
            feat_s1, feat_s2, feat_last, Wg1, bn_g1, Wg2, bn_g2, Wout, bn_out,
            idx_s1, idx_s2, s1h, s2h, frags, as2, t2p, sto, out);
    } else {
        bignn_mfma<false><<<N_TILES, dim3(256), 0, stream>>>(
            feat_s1, feat_s2, feat_last, Wg1, bn_g1, Wg2, bn_g2, Wout, bn_out,
            idx_s1, idx_s2, nullptr, nullptr, nullptr, nullptr, nullptr, nullptr, out);
    }
}

// Round 7
// 65.573 us; speedup vs baseline: 1.8109x; 1.8109x over previous
//
#include <hip/hip_runtime.h>

// BiGNN R7: precompute H = relu(BN(W·g)) for all table rows (dense MFMA,
// one fused prep kernel), then the grouper is a pure gather + packed-f16 max
// that produces p1/p2 directly in MFMA A-frag layout in registers.
// Hot kernel: no LDS, no barriers, no shuffles, no weights; final 192->64
// layer via 24 MFMA with prebuilt Wout frags. Fallback if ws too small.

typedef __attribute__((ext_vector_type(8))) _Float16 half8;
typedef __attribute__((ext_vector_type(4))) int i32x4;
typedef __attribute__((ext_vector_type(4))) float f32x4;
typedef __attribute__((ext_vector_type(2))) _Float16 h2;

constexpr int N_ROWS = 50000;
constexpr int M1 = 200000, M2 = 100000;
constexpr int C1 = 32, C2 = 64, CL = 64, CG = 64;
constexpr float EPS = 1e-3f;
constexpr int N_TILES = N_ROWS / 16;                 // 3125 (exact)

// ---- workspace layout (bytes) ----
constexpr size_t H1_OFF  = 0;                        // [M1][64] f16
constexpr size_t H2_OFF  = (size_t)M1 * CG * 2;      // 25,600,000
constexpr size_t WOF_OFF = H2_OFF + (size_t)M2 * CG * 2;  // 38,400,000
constexpr size_t STO_OFF = WOF_OFF + 24 * 64 * 16;   // +24576
constexpr size_t WS_NEED = STO_OFF + 64 * 8;

// prep grid split
constexpr int NB1 = (M1 + 63) / 64;                  // 3125
constexpr int NB2 = (M2 + 63) / 64;                  // 1563

__device__ __forceinline__ h2 pkrtz(float a, float b) {
    return (h2)__builtin_amdgcn_cvt_pkrtz(a, b);
}
__device__ __forceinline__ half8 pack8f(f32x4 x, f32x4 y) {
    h2 a = pkrtz(x[0], x[1]), b = pkrtz(x[2], x[3]);
    h2 c = pkrtz(y[0], y[1]), d = pkrtz(y[2], y[3]);
    half8 r;
    r[0]=a[0]; r[1]=a[1]; r[2]=b[0]; r[3]=b[1];
    r[4]=c[0]; r[5]=c[1]; r[6]=d[0]; r[7]=d[1];
    return r;
}
__device__ __forceinline__ int pkmax(int a, int b) {
    int d;
    asm("v_pk_max_f16 %0, %1, %2" : "=v"(d) : "v"(a), "v"(b));
    return d;
}
#define MFMA16(a, b, c) __builtin_amdgcn_mfma_f32_16x16x32_f16((a), (b), (c), 0, 0, 0)

// ---- H = relu(BN(tab @ W)) for one 64-row block (device helper) ----
template<int C>
__device__ __forceinline__ void make_h_body(
    const float* __restrict__ tab, const float* __restrict__ W,
    const float* __restrict__ bn, _Float16* __restrict__ H, int M, int blk)
{
    const int t = threadIdx.x, lane = t & 63, lc = lane & 15, hi = lane >> 4;
    const int wave = t >> 6;
    const int base = blk * 64 + wave * 16;

    half8 bW[C / 32][4];
#pragma unroll
    for (int ck = 0; ck < C / 32; ++ck)
#pragma unroll
        for (int nt = 0; nt < 4; ++nt)
#pragma unroll
            for (int j = 0; j < 8; ++j)
                bW[ck][nt][j] = (_Float16)W[(ck * 32 + hi * 8 + j) * CG + nt * 16 + lc];

    const int r32 = min(base + lc, M - 1);
    f32x4 acc[4] = {{0,0,0,0},{0,0,0,0},{0,0,0,0},{0,0,0,0}};
#pragma unroll
    for (int ck = 0; ck < C / 32; ++ck) {
        const f32x4* gp = (const f32x4*)(tab + (size_t)r32 * C + ck * 32 + hi * 8);
        half8 af = pack8f(gp[0], gp[1]);
#pragma unroll
        for (int nt = 0; nt < 4; ++nt) acc[nt] = MFMA16(af, bW[ck][nt], acc[nt]);
    }
#pragma unroll
    for (int nt = 0; nt < 4; ++nt) {
        int ch = nt * 16 + lc;
        float s = bn[ch] * rsqrtf(bn[192 + ch] + EPS);
        float tt = fmaf(-bn[128 + ch], s, bn[64 + ch]);
#pragma unroll
        for (int rg = 0; rg < 4; ++rg) {
            int r = base + hi * 4 + rg;
            if (r < M)
                H[(size_t)r * CG + ch] = (_Float16)fmaxf(0.f, fmaf(s, acc[nt][rg], tt));
        }
    }
}

// ---- fused prep: H1 | H2 | (Wout frags + out-BN consts) ----
__global__ __launch_bounds__(256)
void prep_all(const float* __restrict__ feat_s1, const float* __restrict__ feat_s2,
              const float* __restrict__ Wg1, const float* __restrict__ bn_g1,
              const float* __restrict__ Wg2, const float* __restrict__ bn_g2,
              const float* __restrict__ Wout, const float* __restrict__ bn_out,
              _Float16* __restrict__ H1, _Float16* __restrict__ H2,
              half8* __restrict__ wof, float2* __restrict__ sto)
{
    int blk = blockIdx.x;
    if (blk < NB1) {
        make_h_body<C1>(feat_s1, Wg1, bn_g1, H1, M1, blk);
    } else if (blk < NB1 + NB2) {
        make_h_body<C2>(feat_s2, Wg2, bn_g2, H2, M2, blk - NB1);
    } else {
        for (int g = threadIdx.x; g < 24 * 64 + 64; g += 256) {
            if (g < 24 * 64) {
                int fid = g >> 6, lane = g & 63;
                int ck = fid >> 2, nt = fid & 3, lc = lane & 15, hi = lane >> 4;
                half8 r;
#pragma unroll
                for (int j = 0; j < 8; ++j)
                    r[j] = (_Float16)Wout[(ck * 32 + hi * 8 + j) * CG + nt * 16 + lc];
                wof[g] = r;
            } else {
                int ch = g - 24 * 64;
                float s = bn_out[ch] * rsqrtf(bn_out[192 + ch] + EPS);
                sto[ch] = make_float2(s, fmaf(-bn_out[128 + ch], s, bn_out[64 + ch]));
            }
        }
    }
}

// ---- hot kernel: gather + packed max + final MFMA ----
#define LOADB(HT, I, b, B)                                                     \
    _Pragma("unroll")                                                          \
    for (int u = 0; u < 4; ++u) {                                              \
        const _Float16* s_ = HT + (size_t)(unsigned)I[b][u] * CG + hi * 8;     \
        B[2*u]   = *(const i32x4*)(const void*)s_;                             \
        B[2*u+1] = *(const i32x4*)(const void*)(s_ + 32);                      \
    }
#define MAXB(B, ph0, ph1)                                                      \
    _Pragma("unroll")                                                          \
    for (int u = 0; u < 4; ++u) {                                              \
        _Pragma("unroll")                                                      \
        for (int c_ = 0; c_ < 4; ++c_) {                                       \
            ph0[c_] = pkmax(ph0[c_], B[2*u][c_]);                              \
            ph1[c_] = pkmax(ph1[c_], B[2*u+1][c_]);                            \
        }                                                                      \
    }

__global__ __launch_bounds__(256, 4)
void bignn_gather(const _Float16* __restrict__ H1f, const _Float16* __restrict__ H2f,
                  const float* __restrict__ feat_last,
                  const int* __restrict__ idx_s1, const int* __restrict__ idx_s2,
                  const half8* __restrict__ wof, const float2* __restrict__ sto,
                  float* __restrict__ out)
{
    const int t = threadIdx.x, lane = t & 63, lc = lane & 15, hi = lane >> 4;
    const int wave = t >> 6;
    const int tile = blockIdx.x * 4 + wave;
    if (tile >= N_TILES) return;
    const int base = tile * 16;
    const int row  = base + lc;                       // exact: N_ROWS % 16 == 0

    i32x4 I1[4], I2[4];
#pragma unroll
    for (int b = 0; b < 4; ++b)
        I1[b] = *(const i32x4*)(const void*)(idx_s1 + (size_t)row * 16 + b * 4);

    i32x4 p1h0 = {0,0,0,0}, p1h1 = {0,0,0,0};
    i32x4 p2h0 = {0,0,0,0}, p2h1 = {0,0,0,0};
    i32x4 buf[2][8];

    LOADB(H1f, I1, 0, buf[0]);
    LOADB(H1f, I1, 1, buf[1]);
    MAXB(buf[0], p1h0, p1h1);
    LOADB(H1f, I1, 2, buf[0]);
    // stage T2 indices under T1 work
#pragma unroll
    for (int b = 0; b < 4; ++b)
        I2[b] = *(const i32x4*)(const void*)(idx_s2 + (size_t)row * 16 + b * 4);
    MAXB(buf[1], p1h0, p1h1);
    LOADB(H1f, I1, 3, buf[1]);
    MAXB(buf[0], p1h0, p1h1);
    LOADB(H2f, I2, 0, buf[0]);
    MAXB(buf[1], p1h0, p1h1);
    LOADB(H2f, I2, 1, buf[1]);
    MAXB(buf[0], p2h0, p2h1);
    LOADB(H2f, I2, 2, buf[0]);
    MAXB(buf[1], p2h0, p2h1);
    LOADB(H2f, I2, 3, buf[1]);
    MAXB(buf[0], p2h0, p2h1);
    // feat_last loads under the last max batch
    const f32x4* flp = (const f32x4*)(feat_last + (size_t)row * CL + hi * 8);
    f32x4 f0 = flp[0], f1 = flp[1];
    const f32x4* flq = (const f32x4*)(feat_last + (size_t)row * CL + 32 + hi * 8);
    f32x4 f2 = flq[0], f3 = flq[1];
    MAXB(buf[1], p2h0, p2h1);

    // final layer: A = [feat_last | p1 | p2], 6 k-chunks, all frags in regs
    half8 A[6];
    A[0] = pack8f(f0, f1);
    A[1] = pack8f(f2, f3);
    A[2] = __builtin_bit_cast(half8, p1h0);
    A[3] = __builtin_bit_cast(half8, p1h1);
    A[4] = __builtin_bit_cast(half8, p2h0);
    A[5] = __builtin_bit_cast(half8, p2h1);

    f32x4 facc[4] = {{0,0,0,0},{0,0,0,0},{0,0,0,0},{0,0,0,0}};
#pragma unroll
    for (int ck = 0; ck < 6; ++ck)
#pragma unroll
        for (int nt = 0; nt < 4; ++nt)
            facc[nt] = MFMA16(A[ck], wof[(ck * 4 + nt) * 64 + lane], facc[nt]);

#pragma unroll
    for (int nt = 0; nt < 4; ++nt) {
        float2 so = sto[nt * 16 + lc];
#pragma unroll
        for (int rg = 0; rg < 4; ++rg) {
            int grow = base + hi * 4 + rg;
            out[(size_t)grow * CG + nt * 16 + lc] =
                fmaxf(0.f, fmaf(so.x, facc[nt][rg], so.y));
        }
    }
}

// ---- fallback (ws too small): one block per row, f32, correct but slow ----
__global__ __launch_bounds__(256)
void bignn_ref(const float* __restrict__ feat_s1, const float* __restrict__ feat_s2,
               const float* __restrict__ feat_last,
               const float* __restrict__ Wg1, const float* __restrict__ bn_g1,
               const float* __restrict__ Wg2, const float* __restrict__ bn_g2,
               const float* __restrict__ Wout, const float* __restrict__ bn_out,
               const int* __restrict__ idx_s1, const int* __restrict__ idx_s2,
               float* __restrict__ out)
{
    __shared__ float p[128];
    const int row = blockIdx.x, t = threadIdx.x;
    if (t < 128) {
        const int ch = t & 63;
        const bool g2 = t >= 64;
        const float* bn = g2 ? bn_g2 : bn_g1;
        const float* W  = g2 ? Wg2 : Wg1;
        const float* tab = g2 ? feat_s2 : feat_s1;
        const int*   idx = g2 ? idx_s2 : idx_s1;
        const int C = g2 ? C2 : C1;
        float s = bn[ch] * rsqrtf(bn[192 + ch] + EPS);
        float tt = fmaf(-bn[128 + ch], s, bn[64 + ch]);
        float pv = 0.f;
        for (int k = 0; k < 16; ++k) {
            int nb = idx[(size_t)row * 16 + k];
            float h = 0.f;
            for (int c = 0; c < C; ++c)
                h = fmaf(tab[(size_t)nb * C + c], W[c * CG + ch], h);
            pv = fmaxf(pv, fmaxf(0.f, fmaf(s, h, tt)));
        }
        p[t] = pv;
    }
    __syncthreads();
    if (t < 64) {
        float acc = 0.f;
        for (int j = 0; j < 64; ++j)
            acc = fmaf(feat_last[(size_t)row * CL + j], Wout[j * CG + t], acc);
        for (int j = 0; j < 128; ++j)
            acc = fmaf(p[j], Wout[(64 + j) * CG + t], acc);
        float s = bn_out[t] * rsqrtf(bn_out[192 + t] + EPS);
        float tt = fmaf(-bn_out[128 + t], s, bn_out[64 + t]);
        out[(size_t)row * CG + t] = fmaxf(0.f, fmaf(s, acc, tt));
    }
}

extern "C" void kernel_launch(void* const* d_in, const int* in_sizes, int n_in,
                              void* d_out, int out_size, void* d_ws, size_t ws_size,
                              hipStream_t stream) {
    const float* feat_s1   = (const float*)d_in[0];
    const float* feat_s2   = (const float*)d_in[1];
    const float* feat_last = (const float*)d_in[2];
    const float* Wg1       = (const float*)d_in[3];
    const float* bn_g1     = (const float*)d_in[4];
    const float* Wg2       = (const float*)d_in[5];
    const float* bn_g2     = (const float*)d_in[6];
    const float* Wout      = (const float*)d_in[7];
    const float* bn_out    = (const float*)d_in[8];
    const int*   idx_s1    = (const int*)d_in[9];
    const int*   idx_s2    = (const int*)d_in[10];
    float* out = (float*)d_out;

    if (ws_size >= WS_NEED) {
        _Float16* H1  = (_Float16*)d_ws;
        _Float16* H2  = (_Float16*)((char*)d_ws + H2_OFF);
        half8*    wof = (half8*)((char*)d_ws + WOF_OFF);
        float2*   sto = (float2*)((char*)d_ws + STO_OFF);
        prep_all<<<NB1 + NB2 + 1, 256, 0, stream>>>(
            feat_s1, feat_s2, Wg1, bn_g1, Wg2, bn_g2, Wout, bn_out,
            H1, H2, wof, sto);
        bignn_gather<<<(N_TILES + 3) / 4, 256, 0, stream>>>(
            H1, H2, feat_last, idx_s1, idx_s2, wof, sto, out);
    } else {
        bignn_ref<<<N_ROWS, 256, 0, stream>>>(
            feat_s1, feat_s2, feat_last, Wg1, bn_g1, Wg2, bn_g2, Wout, bn_out,
            idx_s1, idx_s2, out);
    }
}